// Round 10
// baseline (187.718 us; speedup 1.0000x reference)
//
#include <hip/hip_runtime.h>
#include <stdint.h>
#include <math.h>

#define B_ 4
#define T_ 4096
#define C_ 1024
#define H_ 128

// Finite "minus infinity" for the running softmax max: prevents
// exp2(-inf - -inf) = NaN on fully-masked KV tiles (r9 bug: the 128-query
// tile's second diagonal sub-tile is fully masked for lower-half queries).
#define MNEG (-1e30f)

typedef __attribute__((ext_vector_type(8))) short s16x8;   // 8 bf16 (4 VGPRs)
typedef __attribute__((ext_vector_type(4))) float f32x4;   // MFMA accumulator

__device__ __forceinline__ unsigned short f2bf(float f) {
    union { float f; unsigned u; } v; v.f = f;
    unsigned r = v.u + 0x7fffu + ((v.u >> 16) & 1u);
    return (unsigned short)(r >> 16);
}

__device__ __forceinline__ s16x8 as_frag(uint4 u) {
    union { uint4 u; s16x8 s; } v; v.u = u; return v.s;
}

// softmax scale folded into Q at projection time: 1/sqrt(128) * log2(e)
#define QSC (0.0883883476f * 1.4426950408f)

// ---------------------------------------------------------------------------
// Kernel 1: W [1024][128] fp32 -> Wt [3*128][1024] bf16 (transposed, converted)
// ---------------------------------------------------------------------------
__global__ __launch_bounds__(256) void k_wt(const float* __restrict__ Wk,
                                            const float* __restrict__ Wq,
                                            const float* __restrict__ Wv,
                                            unsigned short* __restrict__ Wt) {
    __shared__ float tile[64][65];
    int w = blockIdx.z;  // 0=K, 1=Q, 2=V
    const float* W = (w == 0) ? Wk : (w == 1) ? Wq : Wv;
    int c0 = blockIdx.x * 64, h0 = blockIdx.y * 64;
    int tid = threadIdx.x;
#pragma unroll
    for (int k = 0; k < 16; k++) {
        int idx = tid + k * 256;
        int r = idx >> 6, c = idx & 63;
        tile[r][c] = W[(size_t)(c0 + r) * H_ + h0 + c];
    }
    __syncthreads();
#pragma unroll
    for (int k = 0; k < 16; k++) {
        int idx = tid + k * 256;
        int hh = idx >> 6, cc = idx & 63;
        Wt[(size_t)(w * H_ + h0 + hh) * C_ + c0 + cc] = f2bf(tile[cc][hh]);
    }
}

// ---------------------------------------------------------------------------
// Kernel 2: fused QKV GEMM, LDS double-buffer, ONE barrier per 64-K chunk,
// register ping-pong of Wt B-fragments. (256,3): ~150 regs < 170.
// V written t-permuted within 32-blocks for k_attn's PV fragment order.
// ---------------------------------------------------------------------------
__global__ __launch_bounds__(256, 3) void k_qkv(const float* __restrict__ x,
                                                const unsigned short* __restrict__ Wt,
                                                unsigned short* __restrict__ Qb,
                                                unsigned short* __restrict__ Kb,
                                                unsigned short* __restrict__ Vt) {
    __shared__ unsigned short a_lds[2][64 * 72];  // 2 x 9216 B
    int tid = threadIdx.x;
    int wv = tid >> 6, lane = tid & 63, quad = lane >> 4, lo = lane & 15;
    int r0 = blockIdx.x * 64;
    int cb = blockIdx.y;
    int nt0 = wv * 3;

    f32x4 acc[3][4];
#pragma unroll
    for (int i = 0; i < 3; i++)
#pragma unroll
        for (int j = 0; j < 4; j++) acc[i][j] = (f32x4){0.f, 0.f, 0.f, 0.f};

    const int row_s = tid >> 2;
    const int seg_s = (tid & 3) * 16;
    size_t xbase = (size_t)(r0 + row_s) * C_ + seg_s;

    const unsigned short* wp[3];
#pragma unroll
    for (int nt = 0; nt < 3; nt++)
        wp[nt] = Wt + (size_t)(cb * 192 + (nt0 + nt) * 16 + lo) * C_ + quad * 8;

    auto pack_store = [&](unsigned short* buf, const float4 (&f)[4]) {
        uint4 u0, u1;
        u0.x = (unsigned)f2bf(f[0].x) | ((unsigned)f2bf(f[0].y) << 16);
        u0.y = (unsigned)f2bf(f[0].z) | ((unsigned)f2bf(f[0].w) << 16);
        u0.z = (unsigned)f2bf(f[1].x) | ((unsigned)f2bf(f[1].y) << 16);
        u0.w = (unsigned)f2bf(f[1].z) | ((unsigned)f2bf(f[1].w) << 16);
        u1.x = (unsigned)f2bf(f[2].x) | ((unsigned)f2bf(f[2].y) << 16);
        u1.y = (unsigned)f2bf(f[2].z) | ((unsigned)f2bf(f[2].w) << 16);
        u1.z = (unsigned)f2bf(f[3].x) | ((unsigned)f2bf(f[3].y) << 16);
        u1.w = (unsigned)f2bf(f[3].z) | ((unsigned)f2bf(f[3].w) << 16);
        *(uint4*)&buf[row_s * 72 + seg_s] = u0;
        *(uint4*)&buf[row_s * 72 + seg_s + 8] = u1;
    };
    auto load_x = [&](float4 (&f)[4], int kc) {
        const float* xp = x + xbase + kc * 64;
#pragma unroll
        for (int j = 0; j < 4; j++) f[j] = *(const float4*)(xp + j * 4);
    };
    auto load_b = [&](s16x8 (&b)[3][2], int kc) {
#pragma unroll
        for (int nt = 0; nt < 3; nt++)
#pragma unroll
            for (int kh = 0; kh < 2; kh++)
                b[nt][kh] = *(const s16x8*)(wp[nt] + kc * 64 + kh * 32);
    };
    auto gemm = [&](const unsigned short* buf, const s16x8 (&b)[3][2]) {
        s16x8 af[4][2];
#pragma unroll
        for (int mt = 0; mt < 4; mt++)
#pragma unroll
            for (int kh = 0; kh < 2; kh++)
                af[mt][kh] = *(const s16x8*)&buf[(mt * 16 + lo) * 72 + kh * 32 + quad * 8];
#pragma unroll
        for (int nt = 0; nt < 3; nt++)
#pragma unroll
            for (int kh = 0; kh < 2; kh++)
#pragma unroll
                for (int mt = 0; mt < 4; mt++)
                    acc[nt][mt] = __builtin_amdgcn_mfma_f32_16x16x32_bf16(
                        af[mt][kh], b[nt][kh], acc[nt][mt], 0, 0, 0);
    };

    float4 xr[4];
    s16x8 ba[3][2], bb[3][2];
    load_x(xr, 0);
    load_b(ba, 0);
    pack_store(a_lds[0], xr);
    __syncthreads();

    for (int kc2 = 0; kc2 < 8; kc2++) {
        int e = kc2 * 2;
        float4 xn[4];
        load_x(xn, e + 1);
        load_b(bb, e + 1);
        gemm(a_lds[0], ba);
        pack_store(a_lds[1], xn);
        __syncthreads();
        if (kc2 < 7) { load_x(xn, e + 2); load_b(ba, e + 2); }
        gemm(a_lds[1], bb);
        if (kc2 < 7) pack_store(a_lds[0], xn);
        __syncthreads();
    }

    // Epilogue. C-layout: row = mt*16 + quad*4 + r, col = cb*192 + (nt0+nt)*16 + lo
#pragma unroll
    for (int nt = 0; nt < 3; nt++) {
        int col = cb * 192 + (nt0 + nt) * 16 + lo;
        int w = col >> 7, h = col & 127;
#pragma unroll
        for (int mt = 0; mt < 4; mt++) {
            int mrow = r0 + mt * 16 + quad * 4;
            if (w == 2) {
                int b = mrow >> 12, t0 = mrow & 4095;
                int tp = (t0 & ~31) + (((t0 & 15) >> 2) << 3) + (((t0 >> 4) & 1) << 2);
                uint2 pk;
                pk.x = (unsigned)f2bf(acc[nt][mt][0]) | ((unsigned)f2bf(acc[nt][mt][1]) << 16);
                pk.y = (unsigned)f2bf(acc[nt][mt][2]) | ((unsigned)f2bf(acc[nt][mt][3]) << 16);
                *(uint2*)(Vt + (size_t)(b * H_ + h) * T_ + tp) = pk;
            } else if (w == 1) {
                unsigned short* dst = Qb + (size_t)mrow * H_ + h;
#pragma unroll
                for (int r = 0; r < 4; r++)
                    dst[(size_t)r * H_] = f2bf(acc[nt][mt][r] * QSC);
            } else {
                unsigned short* dst = Kb + (size_t)mrow * H_ + h;
#pragma unroll
                for (int r = 0; r < 4; r++)
                    dst[(size_t)r * H_] = f2bf(acc[nt][mt][r]);
            }
        }
    }
}

// ---------------------------------------------------------------------------
// Kernel 3: causal flash attention, S^T formulation, Q-tile 128, two 16-query
// groups per wave sharing every kf/vf LDS read. m_i starts at FINITE MNEG so
// fully-masked tiles give pv = exp2(-inf - MNEG) = 0, not NaN (r9 bug).
// (256,2): ~190 regs < 256 cap.
// ---------------------------------------------------------------------------
#define LOAD_KV(kv0)                                                            \
    do {                                                                        \
        const uint4* kg = (const uint4*)(Kb + (size_t)(batch * T_ + (kv0) + srow_k) * H_); \
        pk0 = kg[sseg_k + 0]; pk1 = kg[sseg_k + 1];                             \
        pk2 = kg[sseg_k + 2]; pk3 = kg[sseg_k + 3];                             \
        const uint4* vg = (const uint4*)(Vt + (size_t)(batch * H_ + srow_v) * T_ + (kv0)); \
        pv0 = vg[sseg_v + 0]; pv1 = vg[sseg_v + 1];                             \
        pv2 = vg[sseg_v + 2]; pv3 = vg[sseg_v + 3];                             \
    } while (0)

template <int NSPLIT>
__global__ __launch_bounds__(256, 2) void k_attn(const unsigned short* __restrict__ Qb,
                                                 const unsigned short* __restrict__ Kb,
                                                 const unsigned short* __restrict__ Vt,
                                                 float* __restrict__ Opart,
                                                 float* __restrict__ Mpart,
                                                 float* __restrict__ Lpart,
                                                 float* __restrict__ out) {
    __shared__ uint4 kbuf[64 * 16];   // 16 KB
    __shared__ uint4 vbuf[128 * 8];   // 16 KB (t-permuted V^T rows)

    int tid = threadIdx.x;
    int wv = tid >> 6, lane = tid & 63, quad = lane >> 4, lo = lane & 15;

    int id = blockIdx.x;
    int qt = 31 - id / (4 * NSPLIT);   // largest-first (32 q-tiles of 128)
    int rem = id % (4 * NSPLIT);
    int batch = rem / NSPLIT;
    int split = rem % NSPLIT;
    int m0 = qt * 128 + wv * 32;
    int tmax = 2 * qt + 1;             // 64-key tiles covered by this q-tile

    s16x8 qf[2][4];
#pragma unroll
    for (int g = 0; g < 2; g++) {
        size_t qrow = (size_t)(batch * T_ + m0 + 16 * g + lo) * H_;
#pragma unroll
        for (int ks = 0; ks < 4; ks++)
            qf[g][ks] = *(const s16x8*)(Qb + qrow + ks * 32 + quad * 8);
    }

    f32x4 acc_o[2][8];   // O[query][d = o*16 + quad*4 + r]
#pragma unroll
    for (int g = 0; g < 2; g++)
#pragma unroll
        for (int o = 0; o < 8; o++) acc_o[g][o] = (f32x4){0.f, 0.f, 0.f, 0.f};
    float m_i[2] = {MNEG, MNEG}, l_i[2] = {0.f, 0.f};

    const int srow_k = tid >> 2, sseg_k = (tid & 3) * 4;
    const int srow_v = tid >> 1, sseg_v = (tid & 1) * 4;

    uint4 pk0, pk1, pk2, pk3, pv0, pv1, pv2, pv3;
    if (split <= tmax) LOAD_KV(split * 64);

    for (int t = split; t <= tmax; t += NSPLIT) {
        int kv0 = t * 64;
        kbuf[srow_k * 16 + ((sseg_k + 0) ^ (srow_k & 15))] = pk0;
        kbuf[srow_k * 16 + ((sseg_k + 1) ^ (srow_k & 15))] = pk1;
        kbuf[srow_k * 16 + ((sseg_k + 2) ^ (srow_k & 15))] = pk2;
        kbuf[srow_k * 16 + ((sseg_k + 3) ^ (srow_k & 15))] = pk3;
        vbuf[srow_v * 8 + ((sseg_v + 0) ^ (srow_v & 7))] = pv0;
        vbuf[srow_v * 8 + ((sseg_v + 1) ^ (srow_v & 7))] = pv1;
        vbuf[srow_v * 8 + ((sseg_v + 2) ^ (srow_v & 7))] = pv2;
        vbuf[srow_v * 8 + ((sseg_v + 3) ^ (srow_v & 7))] = pv3;
        __syncthreads();
        if (t + NSPLIT <= tmax) LOAD_KV((t + NSPLIT) * 64);

        // S^T = K Q^T for both query groups; each kf read serves both.
        f32x4 s_acc[2][4];
#pragma unroll
        for (int g = 0; g < 2; g++)
#pragma unroll
            for (int nt = 0; nt < 4; nt++) s_acc[g][nt] = (f32x4){0.f, 0.f, 0.f, 0.f};
#pragma unroll
        for (int ks = 0; ks < 4; ks++) {
#pragma unroll
            for (int nt = 0; nt < 4; nt++) {
                s16x8 kf = as_frag(kbuf[(nt * 16 + lo) * 16 + ((ks * 4 + quad) ^ lo)]);
                s_acc[0][nt] = __builtin_amdgcn_mfma_f32_16x16x32_bf16(kf, qf[0][ks], s_acc[0][nt], 0, 0, 0);
                s_acc[1][nt] = __builtin_amdgcn_mfma_f32_16x16x32_bf16(kf, qf[1][ks], s_acc[1][nt], 0, 0, 0);
            }
        }

        float p[2][4][4];
        bool diag = (t >= 2 * qt);
#pragma unroll
        for (int g = 0; g < 2; g++) {
            int query = m0 + 16 * g + lo;
#pragma unroll
            for (int nt = 0; nt < 4; nt++)
#pragma unroll
                for (int r = 0; r < 4; r++) {
                    float sv = s_acc[g][nt][r];
                    if (diag && (kv0 + nt * 16 + quad * 4 + r > query)) sv = -INFINITY;
                    p[g][nt][r] = sv;
                }
        }

        float mnew[2];
        bool upd = false;
#pragma unroll
        for (int g = 0; g < 2; g++) {
            float mx = p[g][0][0];
#pragma unroll
            for (int nt = 0; nt < 4; nt++)
#pragma unroll
                for (int r = 0; r < 4; r++) mx = fmaxf(mx, p[g][nt][r]);
            mx = fmaxf(mx, __shfl_xor(mx, 16));
            mx = fmaxf(mx, __shfl_xor(mx, 32));
            mnew[g] = fmaxf(m_i[g], mx);   // finite: >= MNEG always
            upd |= (mnew[g] > m_i[g]);
        }
        if (__any(upd)) {
#pragma unroll
            for (int g = 0; g < 2; g++) {
                float alpha = exp2f(m_i[g] - mnew[g]);
                l_i[g] *= alpha;
                m_i[g] = mnew[g];
#pragma unroll
                for (int o = 0; o < 8; o++)
#pragma unroll
                    for (int r = 0; r < 4; r++) acc_o[g][o][r] *= alpha;
            }
        }
        s16x8 pf[2][2];
#pragma unroll
        for (int g = 0; g < 2; g++) {
            float rs = 0.f;
#pragma unroll
            for (int nt = 0; nt < 4; nt++)
#pragma unroll
                for (int r = 0; r < 4; r++) {
                    float pv = exp2f(p[g][nt][r] - mnew[g]);  // -inf - finite -> 0
                    p[g][nt][r] = pv;
                    rs += pv;
                }
            rs += __shfl_xor(rs, 16);
            rs += __shfl_xor(rs, 32);
            l_i[g] += rs;
#pragma unroll
            for (int kt = 0; kt < 2; kt++) {
                uint4 u;
                u.x = (__float_as_uint(p[g][2 * kt][0]) >> 16) | ((__float_as_uint(p[g][2 * kt][1]) >> 16) << 16);
                u.y = (__float_as_uint(p[g][2 * kt][2]) >> 16) | ((__float_as_uint(p[g][2 * kt][3]) >> 16) << 16);
                u.z = (__float_as_uint(p[g][2 * kt + 1][0]) >> 16) | ((__float_as_uint(p[g][2 * kt + 1][1]) >> 16) << 16);
                u.w = (__float_as_uint(p[g][2 * kt + 1][2]) >> 16) | ((__float_as_uint(p[g][2 * kt + 1][3]) >> 16) << 16);
                pf[g][kt] = as_frag(u);
            }
        }

        // O^T += V^T P^T; each vf read serves both groups.
#pragma unroll
        for (int kt = 0; kt < 2; kt++)
#pragma unroll
            for (int o = 0; o < 8; o++) {
                int vrow = o * 16 + lo;
                s16x8 vf = as_frag(vbuf[vrow * 8 + ((kt * 4 + quad) ^ (vrow & 7))]);
                acc_o[0][o] = __builtin_amdgcn_mfma_f32_16x16x32_bf16(vf, pf[0][kt], acc_o[0][o], 0, 0, 0);
                acc_o[1][o] = __builtin_amdgcn_mfma_f32_16x16x32_bf16(vf, pf[1][kt], acc_o[1][o], 0, 0, 0);
            }
        __syncthreads();
    }

#pragma unroll
    for (int g = 0; g < 2; g++) {
        int rowg = batch * T_ + m0 + 16 * g + lo;
        if (NSPLIT == 1) {
            float inv = 1.0f / l_i[g];
#pragma unroll
            for (int o = 0; o < 8; o++) {
                float4 v = {acc_o[g][o][0] * inv, acc_o[g][o][1] * inv,
                            acc_o[g][o][2] * inv, acc_o[g][o][3] * inv};
                *(float4*)(out + (size_t)rowg * H_ + o * 16 + quad * 4) = v;
            }
        } else {
            float* Op = Opart + (size_t)split * (16384 * 128);
#pragma unroll
            for (int o = 0; o < 8; o++) {
                float4 v = {acc_o[g][o][0], acc_o[g][o][1], acc_o[g][o][2], acc_o[g][o][3]};
                *(float4*)(Op + (size_t)rowg * H_ + o * 16 + quad * 4) = v;
            }
            if (quad == 0) {
                Mpart[split * 16384 + rowg] = m_i[g];
                Lpart[split * 16384 + rowg] = l_i[g];
            }
        }
    }
}

// ---------------------------------------------------------------------------
// Kernel 4: combine split-KV partials. 8 rows/block, float4 per thread.
// Empty splits carry m=MNEG, l=0 -> weight exp2(MNEG - M) = 0.
// ---------------------------------------------------------------------------
template <int NSPLIT>
__global__ __launch_bounds__(256) void k_comb(const float* __restrict__ Opart,
                                              const float* __restrict__ Mpart,
                                              const float* __restrict__ Lpart,
                                              float* __restrict__ out) {
    int tid = threadIdx.x;
    int row = blockIdx.x * 8 + (tid >> 5);
    int h4 = (tid & 31) * 4;
    float m[NSPLIT], l[NSPLIT];
    float M = MNEG;
#pragma unroll
    for (int s = 0; s < NSPLIT; s++) {
        m[s] = Mpart[s * 16384 + row];
        l[s] = Lpart[s * 16384 + row];
        M = fmaxf(M, m[s]);
    }
    float4 o = {0.f, 0.f, 0.f, 0.f};
    float den = 0.f;
#pragma unroll
    for (int s = 0; s < NSPLIT; s++) {
        float w = exp2f(m[s] - M);
        den += w * l[s];
        float4 v = *(const float4*)(Opart + ((size_t)s * 16384 + row) * H_ + h4);
        o.x += w * v.x; o.y += w * v.y; o.z += w * v.z; o.w += w * v.w;
    }
    float inv = 1.0f / den;
    float4 r = {o.x * inv, o.y * inv, o.z * inv, o.w * inv};
    *(float4*)(out + (size_t)row * H_ + h4) = r;
}

// ---------------------------------------------------------------------------
extern "C" void kernel_launch(void* const* d_in, const int* in_sizes, int n_in,
                              void* d_out, int out_size, void* d_ws, size_t ws_size,
                              hipStream_t stream) {
    const float* x  = (const float*)d_in[0];
    const float* Wk = (const float*)d_in[1];
    const float* Wq = (const float*)d_in[2];
    const float* Wv = (const float*)d_in[3];
    char* ws = (char*)d_ws;
    unsigned short* Wt = (unsigned short*)ws;                 // 768 KB
    unsigned short* Qb = (unsigned short*)(ws + (1u << 20));  // 4 MB
    unsigned short* Kb = (unsigned short*)(ws + (5u << 20));  // 4 MB
    unsigned short* Vt = (unsigned short*)(ws + (9u << 20));  // 4 MB -> end 13 MB
    float* out = (float*)d_out;

    const size_t SPLIT_O = (size_t)16384 * 128 * 4;  // 8 MB per split
    const size_t base = (size_t)13 << 20;
    const size_t need8 = base + 8 * SPLIT_O + 16 * 65536;
    const size_t need4 = base + 4 * SPLIT_O + 8 * 65536;
    const size_t need2 = base + 2 * SPLIT_O + 4 * 65536;

    k_wt  <<<dim3(16, 2, 3), 256, 0, stream>>>(Wk, Wq, Wv, Wt);
    k_qkv <<<dim3(256, 2), 256, 0, stream>>>(x, Wt, Qb, Kb, Vt);

    if (ws_size >= need8) {
        float* Op = (float*)(ws + base);
        float* Mp = (float*)(ws + base + 8 * SPLIT_O);
        float* Lp = (float*)(ws + base + 8 * SPLIT_O + 8 * 65536);
        k_attn<8><<<1024, 256, 0, stream>>>(Qb, Kb, Vt, Op, Mp, Lp, out);
        k_comb<8><<<2048, 256, 0, stream>>>(Op, Mp, Lp, out);
    } else if (ws_size >= need4) {
        float* Op = (float*)(ws + base);
        float* Mp = (float*)(ws + base + 4 * SPLIT_O);
        float* Lp = (float*)(ws + base + 4 * SPLIT_O + 4 * 65536);
        k_attn<4><<<512, 256, 0, stream>>>(Qb, Kb, Vt, Op, Mp, Lp, out);
        k_comb<4><<<2048, 256, 0, stream>>>(Op, Mp, Lp, out);
    } else if (ws_size >= need2) {
        float* Op = (float*)(ws + base);
        float* Mp = (float*)(ws + base + 2 * SPLIT_O);
        float* Lp = (float*)(ws + base + 2 * SPLIT_O + 2 * 65536);
        k_attn<2><<<256, 256, 0, stream>>>(Qb, Kb, Vt, Op, Mp, Lp, out);
        k_comb<2><<<2048, 256, 0, stream>>>(Op, Mp, Lp, out);
    } else {
        k_attn<1><<<128, 256, 0, stream>>>(Qb, Kb, Vt, nullptr, nullptr, nullptr, out);
    }
}

// Round 11
// 173.261 us; speedup vs baseline: 1.0834x; 1.0834x over previous
//
#include <hip/hip_runtime.h>
#include <stdint.h>
#include <math.h>

#define B_ 4
#define T_ 4096
#define C_ 1024
#define H_ 128

// Finite "minus infinity" for running softmax max: exp2(-inf - MNEG) = 0,
// never NaN (r9 lesson; harmless here since r7 tiling has no all-masked tile).
#define MNEG (-1e30f)

typedef __attribute__((ext_vector_type(8))) short s16x8;   // 8 bf16 (4 VGPRs)
typedef __attribute__((ext_vector_type(4))) float f32x4;   // MFMA accumulator

__device__ __forceinline__ unsigned short f2bf(float f) {
    union { float f; unsigned u; } v; v.f = f;
    unsigned r = v.u + 0x7fffu + ((v.u >> 16) & 1u);
    return (unsigned short)(r >> 16);
}

__device__ __forceinline__ s16x8 as_frag(uint4 u) {
    union { uint4 u; s16x8 s; } v; v.u = u; return v.s;
}

// softmax scale folded into Q at projection time: 1/sqrt(128) * log2(e)
#define QSC (0.0883883476f * 1.4426950408f)

// ---------------------------------------------------------------------------
// Kernel 1: W [1024][128] fp32 -> Wt [3*128][1024] bf16 (transposed, converted)
// ---------------------------------------------------------------------------
__global__ __launch_bounds__(256) void k_wt(const float* __restrict__ Wk,
                                            const float* __restrict__ Wq,
                                            const float* __restrict__ Wv,
                                            unsigned short* __restrict__ Wt) {
    __shared__ float tile[64][65];
    int w = blockIdx.z;  // 0=K, 1=Q, 2=V
    const float* W = (w == 0) ? Wk : (w == 1) ? Wq : Wv;
    int c0 = blockIdx.x * 64, h0 = blockIdx.y * 64;
    int tid = threadIdx.x;
#pragma unroll
    for (int k = 0; k < 16; k++) {
        int idx = tid + k * 256;
        int r = idx >> 6, c = idx & 63;
        tile[r][c] = W[(size_t)(c0 + r) * H_ + h0 + c];
    }
    __syncthreads();
#pragma unroll
    for (int k = 0; k < 16; k++) {
        int idx = tid + k * 256;
        int hh = idx >> 6, cc = idx & 63;
        Wt[(size_t)(w * H_ + h0 + hh) * C_ + c0 + cc] = f2bf(tile[cc][hh]);
    }
}

// ---------------------------------------------------------------------------
// Kernel 2: fused QKV GEMM. LDS double-buffer, one barrier per 64-K chunk,
// B-fragment register ping-pong, and x prefetched TWO chunks ahead (xa/xb
// alternating sets; pack happens BEFORE gemm so ds_writes drain during gemm).
// (256,2): grid 512 = 2 blocks/CU (grid-bound), ~210 live regs < 256 cap.
// V written t-permuted within 32-blocks for k_attn's PV fragment order.
// ---------------------------------------------------------------------------
__global__ __launch_bounds__(256, 2) void k_qkv(const float* __restrict__ x,
                                                const unsigned short* __restrict__ Wt,
                                                unsigned short* __restrict__ Qb,
                                                unsigned short* __restrict__ Kb,
                                                unsigned short* __restrict__ Vt) {
    __shared__ unsigned short a_lds[2][64 * 72];  // 2 x 9216 B
    int tid = threadIdx.x;
    int wv = tid >> 6, lane = tid & 63, quad = lane >> 4, lo = lane & 15;
    int r0 = blockIdx.x * 64;
    int cb = blockIdx.y;
    int nt0 = wv * 3;

    f32x4 acc[3][4];
#pragma unroll
    for (int i = 0; i < 3; i++)
#pragma unroll
        for (int j = 0; j < 4; j++) acc[i][j] = (f32x4){0.f, 0.f, 0.f, 0.f};

    const int row_s = tid >> 2;
    const int seg_s = (tid & 3) * 16;
    size_t xbase = (size_t)(r0 + row_s) * C_ + seg_s;

    const unsigned short* wp[3];
#pragma unroll
    for (int nt = 0; nt < 3; nt++)
        wp[nt] = Wt + (size_t)(cb * 192 + (nt0 + nt) * 16 + lo) * C_ + quad * 8;

    auto pack_store = [&](unsigned short* buf, const float4 (&f)[4]) {
        uint4 u0, u1;
        u0.x = (unsigned)f2bf(f[0].x) | ((unsigned)f2bf(f[0].y) << 16);
        u0.y = (unsigned)f2bf(f[0].z) | ((unsigned)f2bf(f[0].w) << 16);
        u0.z = (unsigned)f2bf(f[1].x) | ((unsigned)f2bf(f[1].y) << 16);
        u0.w = (unsigned)f2bf(f[1].z) | ((unsigned)f2bf(f[1].w) << 16);
        u1.x = (unsigned)f2bf(f[2].x) | ((unsigned)f2bf(f[2].y) << 16);
        u1.y = (unsigned)f2bf(f[2].z) | ((unsigned)f2bf(f[2].w) << 16);
        u1.z = (unsigned)f2bf(f[3].x) | ((unsigned)f2bf(f[3].y) << 16);
        u1.w = (unsigned)f2bf(f[3].z) | ((unsigned)f2bf(f[3].w) << 16);
        *(uint4*)&buf[row_s * 72 + seg_s] = u0;
        *(uint4*)&buf[row_s * 72 + seg_s + 8] = u1;
    };
    auto load_x = [&](float4 (&f)[4], int kc) {
        const float* xp = x + xbase + kc * 64;
#pragma unroll
        for (int j = 0; j < 4; j++) f[j] = *(const float4*)(xp + j * 4);
    };
    auto load_b = [&](s16x8 (&b)[3][2], int kc) {
#pragma unroll
        for (int nt = 0; nt < 3; nt++)
#pragma unroll
            for (int kh = 0; kh < 2; kh++)
                b[nt][kh] = *(const s16x8*)(wp[nt] + kc * 64 + kh * 32);
    };
    auto gemm = [&](const unsigned short* buf, const s16x8 (&b)[3][2]) {
        s16x8 af[4][2];
#pragma unroll
        for (int mt = 0; mt < 4; mt++)
#pragma unroll
            for (int kh = 0; kh < 2; kh++)
                af[mt][kh] = *(const s16x8*)&buf[(mt * 16 + lo) * 72 + kh * 32 + quad * 8];
#pragma unroll
        for (int nt = 0; nt < 3; nt++)
#pragma unroll
            for (int kh = 0; kh < 2; kh++)
#pragma unroll
                for (int mt = 0; mt < 4; mt++)
                    acc[nt][mt] = __builtin_amdgcn_mfma_f32_16x16x32_bf16(
                        af[mt][kh], b[nt][kh], acc[nt][mt], 0, 0, 0);
    };

    float4 xa[4], xb[4];
    s16x8 ba[3][2], bb[3][2];
    load_x(xa, 0);      // x0
    load_x(xb, 1);      // x1  (2-deep x pipeline)
    load_b(ba, 0);      // b0
    pack_store(a_lds[0], xa);
    __syncthreads();

    for (int kc2 = 0; kc2 < 8; kc2++) {
        int e = 2 * kc2;
        // even chunk e: consume buf0/ba
        if (e + 2 < 16) load_x(xa, e + 2);   // xa freed (x_e packed); fetch x_{e+2}
        load_b(bb, e + 1);
        pack_store(a_lds[1], xb);            // x_{e+1} -> buf1 (loaded >=1 phase ago)
        gemm(a_lds[0], ba);
        __syncthreads();
        // odd chunk e+1: consume buf1/bb
        if (e + 3 < 16) load_x(xb, e + 3);
        if (e + 2 < 16) {
            load_b(ba, e + 2);
            pack_store(a_lds[0], xa);        // x_{e+2} -> buf0
        }
        gemm(a_lds[1], bb);
        __syncthreads();
    }

    // Epilogue. C-layout: row = mt*16 + quad*4 + r, col = cb*192 + (nt0+nt)*16 + lo
#pragma unroll
    for (int nt = 0; nt < 3; nt++) {
        int col = cb * 192 + (nt0 + nt) * 16 + lo;
        int w = col >> 7, h = col & 127;
#pragma unroll
        for (int mt = 0; mt < 4; mt++) {
            int mrow = r0 + mt * 16 + quad * 4;
            if (w == 2) {
                int b = mrow >> 12, t0 = mrow & 4095;
                int tp = (t0 & ~31) + (((t0 & 15) >> 2) << 3) + (((t0 >> 4) & 1) << 2);
                uint2 pk;
                pk.x = (unsigned)f2bf(acc[nt][mt][0]) | ((unsigned)f2bf(acc[nt][mt][1]) << 16);
                pk.y = (unsigned)f2bf(acc[nt][mt][2]) | ((unsigned)f2bf(acc[nt][mt][3]) << 16);
                *(uint2*)(Vt + (size_t)(b * H_ + h) * T_ + tp) = pk;
            } else if (w == 1) {
                unsigned short* dst = Qb + (size_t)mrow * H_ + h;
#pragma unroll
                for (int r = 0; r < 4; r++)
                    dst[(size_t)r * H_] = f2bf(acc[nt][mt][r] * QSC);
            } else {
                unsigned short* dst = Kb + (size_t)mrow * H_ + h;
#pragma unroll
                for (int r = 0; r < 4; r++)
                    dst[(size_t)r * H_] = f2bf(acc[nt][mt][r]);
            }
        }
    }
}

// ---------------------------------------------------------------------------
// Kernel 3: causal flash attention — r7 PROVEN version (43.9 µs): S^T
// formulation, 64-query tiles, one 16-query group per wave, register K/V
// prefetch (explicit scalars), trunc P-pack into B-frags, rescale-skip,
// V key-permuted at projection. (256,3): ~145 regs (VGPR+AGPR) < 170 cap.
// ---------------------------------------------------------------------------
#define LOAD_KV(kv0)                                                            \
    do {                                                                        \
        const uint4* kg = (const uint4*)(Kb + (size_t)(batch * T_ + (kv0) + srow_k) * H_); \
        pk0 = kg[sseg_k + 0]; pk1 = kg[sseg_k + 1];                             \
        pk2 = kg[sseg_k + 2]; pk3 = kg[sseg_k + 3];                             \
        const uint4* vg = (const uint4*)(Vt + (size_t)(batch * H_ + srow_v) * T_ + (kv0)); \
        pv0 = vg[sseg_v + 0]; pv1 = vg[sseg_v + 1];                             \
        pv2 = vg[sseg_v + 2]; pv3 = vg[sseg_v + 3];                             \
    } while (0)

template <int NSPLIT>
__global__ __launch_bounds__(256, 3) void k_attn(const unsigned short* __restrict__ Qb,
                                                 const unsigned short* __restrict__ Kb,
                                                 const unsigned short* __restrict__ Vt,
                                                 float* __restrict__ Opart,
                                                 float* __restrict__ Mpart,
                                                 float* __restrict__ Lpart,
                                                 float* __restrict__ out) {
    __shared__ uint4 kbuf[64 * 16];   // 16 KB
    __shared__ uint4 vbuf[128 * 8];   // 16 KB (t-permuted V^T rows)

    int tid = threadIdx.x;
    int wv = tid >> 6, lane = tid & 63, quad = lane >> 4, lo = lane & 15;

    int id = blockIdx.x;
    int qt = 63 - id / (4 * NSPLIT);   // largest-first
    int rem = id % (4 * NSPLIT);
    int batch = rem / NSPLIT;
    int split = rem % NSPLIT;
    int m0 = qt * 64 + wv * 16;
    int query = m0 + lo;

    s16x8 qf[4];
    size_t qrow = (size_t)(batch * T_ + m0 + lo) * H_;
#pragma unroll
    for (int ks = 0; ks < 4; ks++)
        qf[ks] = *(const s16x8*)(Qb + qrow + ks * 32 + quad * 8);

    f32x4 acc_o[8];   // O[query=lo][d = o*16 + quad*4 + r]
#pragma unroll
    for (int o = 0; o < 8; o++) acc_o[o] = (f32x4){0.f, 0.f, 0.f, 0.f};
    float m_i = MNEG, l_i = 0.f;

    const int srow_k = tid >> 2, sseg_k = (tid & 3) * 4;
    const int srow_v = tid >> 1, sseg_v = (tid & 1) * 4;

    uint4 pk0, pk1, pk2, pk3, pv0, pv1, pv2, pv3;
    if (split <= qt) LOAD_KV(split * 64);

    for (int t = split; t <= qt; t += NSPLIT) {
        int kv0 = t * 64;
        kbuf[srow_k * 16 + ((sseg_k + 0) ^ (srow_k & 15))] = pk0;
        kbuf[srow_k * 16 + ((sseg_k + 1) ^ (srow_k & 15))] = pk1;
        kbuf[srow_k * 16 + ((sseg_k + 2) ^ (srow_k & 15))] = pk2;
        kbuf[srow_k * 16 + ((sseg_k + 3) ^ (srow_k & 15))] = pk3;
        vbuf[srow_v * 8 + ((sseg_v + 0) ^ (srow_v & 7))] = pv0;
        vbuf[srow_v * 8 + ((sseg_v + 1) ^ (srow_v & 7))] = pv1;
        vbuf[srow_v * 8 + ((sseg_v + 2) ^ (srow_v & 7))] = pv2;
        vbuf[srow_v * 8 + ((sseg_v + 3) ^ (srow_v & 7))] = pv3;
        __syncthreads();
        if (t + NSPLIT <= qt) LOAD_KV((t + NSPLIT) * 64);

        // S^T = K Q^T: lane holds S[query=lo][key = kv0 + nt*16 + quad*4 + r]
        f32x4 s_acc[4];
#pragma unroll
        for (int nt = 0; nt < 4; nt++) s_acc[nt] = (f32x4){0.f, 0.f, 0.f, 0.f};
#pragma unroll
        for (int ks = 0; ks < 4; ks++) {
#pragma unroll
            for (int nt = 0; nt < 4; nt++) {
                s16x8 kf = as_frag(kbuf[(nt * 16 + lo) * 16 + ((ks * 4 + quad) ^ lo)]);
                s_acc[nt] = __builtin_amdgcn_mfma_f32_16x16x32_bf16(kf, qf[ks], s_acc[nt], 0, 0, 0);
            }
        }

        float p[4][4];
        bool diag = (t == qt);
#pragma unroll
        for (int nt = 0; nt < 4; nt++)
#pragma unroll
            for (int r = 0; r < 4; r++) {
                float sv = s_acc[nt][r];
                if (diag && (kv0 + nt * 16 + quad * 4 + r > query)) sv = -INFINITY;
                p[nt][r] = sv;
            }

        float mx = p[0][0];
#pragma unroll
        for (int nt = 0; nt < 4; nt++)
#pragma unroll
            for (int r = 0; r < 4; r++) mx = fmaxf(mx, p[nt][r]);
        mx = fmaxf(mx, __shfl_xor(mx, 16));
        mx = fmaxf(mx, __shfl_xor(mx, 32));
        float mnew = fmaxf(m_i, mx);
        if (__any(mnew > m_i)) {
            float alpha = exp2f(m_i - mnew);
            l_i *= alpha;
            m_i = mnew;
#pragma unroll
            for (int o = 0; o < 8; o++)
#pragma unroll
                for (int r = 0; r < 4; r++) acc_o[o][r] *= alpha;
        }
        float rs = 0.f;
#pragma unroll
        for (int nt = 0; nt < 4; nt++)
#pragma unroll
            for (int r = 0; r < 4; r++) {
                float pv = exp2f(p[nt][r] - mnew);
                p[nt][r] = pv;
                rs += pv;
            }
        rs += __shfl_xor(rs, 16);
        rs += __shfl_xor(rs, 32);
        l_i += rs;

        // pack P straight into B-fragments (truncation; P in [0,1])
        s16x8 pf[2];
#pragma unroll
        for (int kt = 0; kt < 2; kt++) {
            uint4 u;
            u.x = (__float_as_uint(p[2 * kt][0]) >> 16) | ((__float_as_uint(p[2 * kt][1]) >> 16) << 16);
            u.y = (__float_as_uint(p[2 * kt][2]) >> 16) | ((__float_as_uint(p[2 * kt][3]) >> 16) << 16);
            u.z = (__float_as_uint(p[2 * kt + 1][0]) >> 16) | ((__float_as_uint(p[2 * kt + 1][1]) >> 16) << 16);
            u.w = (__float_as_uint(p[2 * kt + 1][2]) >> 16) | ((__float_as_uint(p[2 * kt + 1][3]) >> 16) << 16);
            pf[kt] = as_frag(u);
        }

        // O^T += V^T P^T  (A = vf from permuted vbuf, B = pf)
#pragma unroll
        for (int kt = 0; kt < 2; kt++)
#pragma unroll
            for (int o = 0; o < 8; o++) {
                int vrow = o * 16 + lo;
                s16x8 vf = as_frag(vbuf[vrow * 8 + ((kt * 4 + quad) ^ (vrow & 7))]);
                acc_o[o] = __builtin_amdgcn_mfma_f32_16x16x32_bf16(vf, pf[kt], acc_o[o], 0, 0, 0);
            }
        __syncthreads();
    }

    int rowg = batch * T_ + m0 + lo;
    if (NSPLIT == 1) {
        float inv = 1.0f / l_i;
#pragma unroll
        for (int o = 0; o < 8; o++) {
            float4 v = {acc_o[o][0] * inv, acc_o[o][1] * inv,
                        acc_o[o][2] * inv, acc_o[o][3] * inv};
            *(float4*)(out + (size_t)rowg * H_ + o * 16 + quad * 4) = v;
        }
    } else {
        float* Op = Opart + (size_t)split * (16384 * 128);
#pragma unroll
        for (int o = 0; o < 8; o++) {
            float4 v = {acc_o[o][0], acc_o[o][1], acc_o[o][2], acc_o[o][3]};
            *(float4*)(Op + (size_t)rowg * H_ + o * 16 + quad * 4) = v;
        }
        if (quad == 0) {
            Mpart[split * 16384 + rowg] = m_i;
            Lpart[split * 16384 + rowg] = l_i;
        }
    }
}

// ---------------------------------------------------------------------------
// Kernel 4: combine split-KV partials. 8 rows/block, float4 per thread.
// Empty splits carry m=MNEG, l=0 -> weight exp2(MNEG - M) = 0.
// ---------------------------------------------------------------------------
template <int NSPLIT>
__global__ __launch_bounds__(256) void k_comb(const float* __restrict__ Opart,
                                              const float* __restrict__ Mpart,
                                              const float* __restrict__ Lpart,
                                              float* __restrict__ out) {
    int tid = threadIdx.x;
    int row = blockIdx.x * 8 + (tid >> 5);
    int h4 = (tid & 31) * 4;
    float m[NSPLIT], l[NSPLIT];
    float M = MNEG;
#pragma unroll
    for (int s = 0; s < NSPLIT; s++) {
        m[s] = Mpart[s * 16384 + row];
        l[s] = Lpart[s * 16384 + row];
        M = fmaxf(M, m[s]);
    }
    float4 o = {0.f, 0.f, 0.f, 0.f};
    float den = 0.f;
#pragma unroll
    for (int s = 0; s < NSPLIT; s++) {
        float w = exp2f(m[s] - M);
        den += w * l[s];
        float4 v = *(const float4*)(Opart + ((size_t)s * 16384 + row) * H_ + h4);
        o.x += w * v.x; o.y += w * v.y; o.z += w * v.z; o.w += w * v.w;
    }
    float inv = 1.0f / den;
    float4 r = {o.x * inv, o.y * inv, o.z * inv, o.w * inv};
    *(float4*)(out + (size_t)row * H_ + h4) = r;
}

// ---------------------------------------------------------------------------
extern "C" void kernel_launch(void* const* d_in, const int* in_sizes, int n_in,
                              void* d_out, int out_size, void* d_ws, size_t ws_size,
                              hipStream_t stream) {
    const float* x  = (const float*)d_in[0];
    const float* Wk = (const float*)d_in[1];
    const float* Wq = (const float*)d_in[2];
    const float* Wv = (const float*)d_in[3];
    char* ws = (char*)d_ws;
    unsigned short* Wt = (unsigned short*)ws;                 // 768 KB
    unsigned short* Qb = (unsigned short*)(ws + (1u << 20));  // 4 MB
    unsigned short* Kb = (unsigned short*)(ws + (5u << 20));  // 4 MB
    unsigned short* Vt = (unsigned short*)(ws + (9u << 20));  // 4 MB -> end 13 MB
    float* out = (float*)d_out;

    const size_t SPLIT_O = (size_t)16384 * 128 * 4;  // 8 MB per split
    const size_t base = (size_t)13 << 20;
    const size_t need4 = base + 4 * SPLIT_O + 8 * 65536;
    const size_t need2 = base + 2 * SPLIT_O + 4 * 65536;

    k_wt  <<<dim3(16, 2, 3), 256, 0, stream>>>(Wk, Wq, Wv, Wt);
    k_qkv <<<dim3(256, 2), 256, 0, stream>>>(x, Wt, Qb, Kb, Vt);

    if (ws_size >= need4) {
        float* Op = (float*)(ws + base);
        float* Mp = (float*)(ws + base + 4 * SPLIT_O);
        float* Lp = (float*)(ws + base + 4 * SPLIT_O + 4 * 65536);
        k_attn<4><<<1024, 256, 0, stream>>>(Qb, Kb, Vt, Op, Mp, Lp, out);
        k_comb<4><<<2048, 256, 0, stream>>>(Op, Mp, Lp, out);
    } else if (ws_size >= need2) {
        float* Op = (float*)(ws + base);
        float* Mp = (float*)(ws + base + 2 * SPLIT_O);
        float* Lp = (float*)(ws + base + 2 * SPLIT_O + 2 * 65536);
        k_attn<2><<<512, 256, 0, stream>>>(Qb, Kb, Vt, Op, Mp, Lp, out);
        k_comb<2><<<2048, 256, 0, stream>>>(Op, Mp, Lp, out);
    } else {
        k_attn<1><<<256, 256, 0, stream>>>(Qb, Kb, Vt, nullptr, nullptr, nullptr, out);
    }
}